// Round 6
// baseline (1140.482 us; speedup 1.0000x reference)
//
#include <hip/hip_runtime.h>
#include <hip/hip_fp16.h>
#include <math.h>

#define NN 100000
#define NE 3200000
#define NG 1024
#define FDIM 128
#define NFC1 64
#define NFC2 10

#define BSHIFT 9
#define NBUCK 196   // ceil(NN/512)
#define CAP 20480   // mean 16384, sigma ~127 -> 32-sigma headroom
#define EPB 16      // edges per thread in bin_kernel

#define RF(x) __builtin_amdgcn_readfirstlane(x)

// ---------------- pass 1: bin edges into 196 coarse buckets ----------------
// Packed value: (dst & 511) << 17 | src   (src < 2^17, dst_local < 2^9)
__global__ __launch_bounds__(256) void bin_kernel(const int* __restrict__ src,
                                                  const int* __restrict__ dst,
                                                  int* __restrict__ gcursor,
                                                  int* __restrict__ staging) {
  __shared__ int hist[NBUCK];
  __shared__ int base[NBUCK];
  int t = threadIdx.x;
  for (int i = t; i < NBUCK; i += 256) hist[i] = 0;
  __syncthreads();
  size_t e0 = (size_t)blockIdx.x * (256 * EPB);
  int bk[EPB], rank[EPB], val[EPB];
#pragma unroll
  for (int j = 0; j < EPB; ++j) {
    size_t e = e0 + (size_t)j * 256 + t;
    if (e < NE) {
      int d = dst[e];
      int s = src[e];
      bk[j] = d >> BSHIFT;
      val[j] = ((d & 511) << 17) | s;
      rank[j] = atomicAdd(&hist[bk[j]], 1);
    } else {
      bk[j] = -1;
    }
  }
  __syncthreads();
  for (int i = t; i < NBUCK; i += 256) base[i] = atomicAdd(&gcursor[i], hist[i]);
  __syncthreads();
#pragma unroll
  for (int j = 0; j < EPB; ++j) {
    if (bk[j] >= 0) {
      int pos = base[bk[j]] + rank[j];
      if (pos < CAP) staging[(size_t)bk[j] * CAP + pos] = val[j];
    }
  }
}

// ---------------- pass 2: per-bucket CSR finalize (scan fused in) ----------------
__global__ __launch_bounds__(256) void build_kernel(const int* __restrict__ staging,
                                                    const int* __restrict__ gcursor,
                                                    int* __restrict__ row_off,
                                                    int* __restrict__ esrc) {
  __shared__ int ncnt[512];
  __shared__ int noff[513];
  __shared__ int part[256];
  __shared__ int sscan[256];
  int b = blockIdx.x, t = threadIdx.x;
  int gv = (t < NBUCK) ? gcursor[t] : 0;
  sscan[t] = gv;
  __syncthreads();
  for (int st = 1; st < 256; st <<= 1) {
    int u = (t >= st) ? sscan[t - st] : 0;
    __syncthreads();
    sscan[t] += u;
    __syncthreads();
  }
  int cnt = gcursor[b];
  int ebase = sscan[b] - cnt;  // exclusive prefix
  int nbase = b << BSHIFT;
  ncnt[t] = 0;
  ncnt[t + 256] = 0;
  __syncthreads();
  const int* sp = staging + (size_t)b * CAP;
  for (int i = t; i < cnt; i += 256) {
    int dl = sp[i] >> 17;
    atomicAdd(&ncnt[dl], 1);
  }
  __syncthreads();
  int a0 = ncnt[2 * t], a1 = ncnt[2 * t + 1];
  part[t] = a0 + a1;
  __syncthreads();
  for (int st = 1; st < 256; st <<= 1) {
    int u = (t >= st) ? part[t - st] : 0;
    __syncthreads();
    part[t] += u;
    __syncthreads();
  }
  int excl = (t > 0) ? part[t - 1] : 0;
  noff[2 * t] = excl;
  noff[2 * t + 1] = excl + a0;
  if (t == 255) noff[512] = part[255];
  __syncthreads();
  for (int i = t; i <= 512; i += 256) {
    int n = nbase + i;
    if (n <= NN) row_off[n] = ebase + noff[i];
  }
  ncnt[2 * t] = noff[2 * t];
  ncnt[2 * t + 1] = noff[2 * t + 1];
  __syncthreads();
  for (int i = t; i < cnt; i += 256) {
    int v = sp[i];
    int dl = v >> 17;
    int pos = atomicAdd(&ncnt[dl], 1);
    esrc[ebase + pos] = v & 0x1FFFF;
  }
}

// ---------------- fp32 -> fp16 cast of node_attr ----------------
__global__ __launch_bounds__(256) void cast_f16(const float4* __restrict__ in,
                                                ushort4* __restrict__ out, int n4) {
  int i = blockIdx.x * 256 + threadIdx.x;
  if (i < n4) {
    float4 v = in[i];
    ushort4 o;
    o.x = __half_as_ushort(__float2half(v.x));
    o.y = __half_as_ushort(__float2half(v.y));
    o.z = __half_as_ushort(__float2half(v.z));
    o.w = __half_as_ushort(__float2half(v.w));
    out[i] = o;
  }
}

// ---------------- fused conv layer: outh = f16(relu(gather(xin_f16)@W + bias)) ----------------
// 512 threads = 8 waves; 64 dst nodes per block. Gather at fp16: rows are 256B;
// each half-wave (32 lanes x ushort4 = 256B) streams one edge row, 8 edges in
// flight per half (16 rows/wave). Accumulate fp32 in registers; combine halves
// via shfl_xor(32); row-major LDS tile (b128 writes, broadcast b128 reads);
// fp32 GEMM; fp16 store.
__global__ __launch_bounds__(512) void conv_fused(const ushort4* __restrict__ xin,
                                                  const int* __restrict__ row_off,
                                                  const int* __restrict__ esrc,
                                                  const float* __restrict__ W,
                                                  const float* __restrict__ bias,
                                                  ushort* __restrict__ outh) {
  __shared__ __align__(16) float aR[64 * 132];
  int t = threadIdx.x;
  int w = t >> 6;
  int lane = t & 63;
  int h = lane >> 5;
  int l32 = lane & 31;
  int nodebase = blockIdx.x * 64;
  int r0 = w * 8;

  // ---- phase 1: gather-aggregate 8 nodes for this wave ----
  for (int i = 0; i < 8; ++i) {
    int r = r0 + i;
    int node = nodebase + r;
    int beg = 0, end = 0;
    if (node < NN) {
      beg = RF(row_off[node]);
      end = RF(row_off[node + 1]);
    }
    float4 acc = make_float4(0.f, 0.f, 0.f, 0.f);
    int e = beg;
    for (; e + 16 <= end; e += 16) {
      int idx[16];
#pragma unroll
      for (int j = 0; j < 16; ++j) idx[j] = RF(esrc[e + j]);
      ushort4 v[8];
#pragma unroll
      for (int j = 0; j < 8; ++j) {
        int row = h ? idx[2 * j + 1] : idx[2 * j];
        v[j] = xin[(size_t)row * 32 + l32];
      }
#pragma unroll
      for (int j = 0; j < 8; ++j) {
        acc.x += __half2float(__ushort_as_half(v[j].x));
        acc.y += __half2float(__ushort_as_half(v[j].y));
        acc.z += __half2float(__ushort_as_half(v[j].z));
        acc.w += __half2float(__ushort_as_half(v[j].w));
      }
    }
    for (; e + 2 <= end; e += 2) {
      int i0 = RF(esrc[e]);
      int i1 = RF(esrc[e + 1]);
      int row = h ? i1 : i0;
      ushort4 v = xin[(size_t)row * 32 + l32];
      acc.x += __half2float(__ushort_as_half(v.x));
      acc.y += __half2float(__ushort_as_half(v.y));
      acc.z += __half2float(__ushort_as_half(v.z));
      acc.w += __half2float(__ushort_as_half(v.w));
    }
    if (e < end) {  // single leftover edge: counted by half 0 only
      int i0 = RF(esrc[e]);
      ushort4 v = xin[(size_t)i0 * 32 + l32];
      if (h == 0) {
        acc.x += __half2float(__ushort_as_half(v.x));
        acc.y += __half2float(__ushort_as_half(v.y));
        acc.z += __half2float(__ushort_as_half(v.z));
        acc.w += __half2float(__ushort_as_half(v.w));
      }
    }
    // combine the two half-waves (both halves end with the full sum)
    acc.x += __shfl_xor(acc.x, 32, 64);
    acc.y += __shfl_xor(acc.y, 32, 64);
    acc.z += __shfl_xor(acc.z, 32, 64);
    acc.w += __shfl_xor(acc.w, 32, 64);
    if (h == 0) {
      *(float4*)&aR[r * 132 + 4 * l32] = acc;  // row-major, b128, conflict-light
    }
  }
  __syncthreads();

  // ---- phase 2: GEMM 64x128 tile, k-step 4 with b128 broadcast A reads ----
  int rg = lane >> 5;
  int c = lane & 31;  // cols 4c..4c+3
  int rbase = r0 + rg * 4;

  float acc2[4][4];
#pragma unroll
  for (int r = 0; r < 4; ++r)
#pragma unroll
    for (int j = 0; j < 4; ++j) acc2[r][j] = 0.f;

#pragma unroll 2
  for (int k = 0; k < 128; k += 4) {
    float4 b0 = *(const float4*)(W + (k + 0) * FDIM + c * 4);
    float4 b1 = *(const float4*)(W + (k + 1) * FDIM + c * 4);
    float4 b2 = *(const float4*)(W + (k + 2) * FDIM + c * 4);
    float4 b3 = *(const float4*)(W + (k + 3) * FDIM + c * 4);
    float4 a[4];
    a[0] = *(const float4*)&aR[(rbase + 0) * 132 + k];
    a[1] = *(const float4*)&aR[(rbase + 1) * 132 + k];
    a[2] = *(const float4*)&aR[(rbase + 2) * 132 + k];
    a[3] = *(const float4*)&aR[(rbase + 3) * 132 + k];
#pragma unroll
    for (int r = 0; r < 4; ++r) {
      acc2[r][0] += a[r].x * b0.x + a[r].y * b1.x + a[r].z * b2.x + a[r].w * b3.x;
      acc2[r][1] += a[r].x * b0.y + a[r].y * b1.y + a[r].z * b2.y + a[r].w * b3.y;
      acc2[r][2] += a[r].x * b0.z + a[r].y * b1.z + a[r].z * b2.z + a[r].w * b3.z;
      acc2[r][3] += a[r].x * b0.w + a[r].y * b1.w + a[r].z * b2.w + a[r].w * b3.w;
    }
  }

  float4 b4 = *(const float4*)(bias + c * 4);
#pragma unroll
  for (int r = 0; r < 4; ++r) {
    int row = nodebase + rbase + r;
    if (row < NN) {
      ushort4 o;
      o.x = __half_as_ushort(__float2half(fmaxf(acc2[r][0] + b4.x, 0.f)));
      o.y = __half_as_ushort(__float2half(fmaxf(acc2[r][1] + b4.y, 0.f)));
      o.z = __half_as_ushort(__float2half(fmaxf(acc2[r][2] + b4.z, 0.f)));
      o.w = __half_as_ushort(__float2half(fmaxf(acc2[r][3] + b4.w, 0.f)));
      *(ushort4*)(outh + (size_t)row * FDIM + c * 4) = o;
    }
  }
}

// ---------------- fused global pool + FC1 + FC2 + softmax ----------------
__device__ int lower_bound_dev(const int* __restrict__ arr, int n, int val) {
  int lo = 0, hi = n;
  while (lo < hi) {
    int mid = (lo + hi) >> 1;
    if (arr[mid] < val) lo = mid + 1; else hi = mid;
  }
  return lo;
}

__global__ __launch_bounds__(128) void pool_head(const ushort* __restrict__ x,
                                                 const int* __restrict__ batching,
                                                 const float* __restrict__ Wf1,
                                                 const float* __restrict__ bf1,
                                                 const float* __restrict__ Wf2,
                                                 const float* __restrict__ bf2,
                                                 float* __restrict__ out) {
  __shared__ int se, ee;
  __shared__ float gl[128];
  __shared__ float hl[64];
  __shared__ float ol[10];
  __shared__ float red[2];
  int gid = blockIdx.x, t = threadIdx.x;
  if (t == 0) {
    se = lower_bound_dev(batching, NN, gid);
    ee = lower_bound_dev(batching, NN, gid + 1);
  }
  __syncthreads();
  float acc = 0.f;
  for (int n = se; n < ee; ++n) acc += __half2float(__ushort_as_half(x[(size_t)n * FDIM + t]));
  gl[t] = acc;
  __syncthreads();
  if (t < NFC1) {
    float h = bf1[t];
    for (int f = 0; f < 128; ++f) h += gl[f] * Wf1[f * NFC1 + t];
    hl[t] = h;
  }
  __syncthreads();
  if (t < NFC2) {
    float o = bf2[t];
    for (int i = 0; i < NFC1; ++i) o += hl[i] * Wf2[i * NFC2 + t];
    ol[t] = o;
  }
  __syncthreads();
  if (t == 0) {
    float m = ol[0];
    for (int i = 1; i < NFC2; ++i) m = fmaxf(m, ol[i]);
    float s = 0.f;
    for (int i = 0; i < NFC2; ++i) s += expf(ol[i] - m);
    red[0] = m;
    red[1] = s;
  }
  __syncthreads();
  if (t < NFC2) out[(size_t)gid * NFC2 + t] = expf(ol[t] - red[0]) / red[1];
}

extern "C" void kernel_launch(void* const* d_in, const int* in_sizes, int n_in,
                              void* d_out, int out_size, void* d_ws, size_t ws_size,
                              hipStream_t stream) {
  const float* node_attr = (const float*)d_in[0];
  const float* Wc = (const float*)d_in[1];   // [3][128][128]
  const float* bc = (const float*)d_in[2];   // [3][128]
  const float* Wf1 = (const float*)d_in[3];  // [128][64]
  const float* bf1 = (const float*)d_in[4];
  const float* Wf2 = (const float*)d_in[5];  // [64][10]
  const float* bf2 = (const float*)d_in[6];
  const int* src = (const int*)d_in[7];
  const int* dst = (const int*)d_in[8];
  const int* batching = (const int*)d_in[9];
  float* out = (float*)d_out;

  char* wsp = (char*)d_ws;
  size_t off = 0;
  auto alloc = [&](size_t bytes) -> void* {
    void* p = wsp + off;
    off += (bytes + 255) & ~(size_t)255;
    return p;
  };
  int* row_off = (int*)alloc((size_t)(NN + 1) * sizeof(int));
  int* gcursor = (int*)alloc(NBUCK * sizeof(int));
  int* esrc = (int*)alloc((size_t)NE * sizeof(int));
  ushort* xh = (ushort*)alloc((size_t)NN * FDIM * sizeof(ushort));    // fp16 input
  ushort* bufA = (ushort*)alloc((size_t)NN * FDIM * sizeof(ushort));  // fp16
  ushort* bufB = (ushort*)alloc((size_t)NN * FDIM * sizeof(ushort));  // fp16
  // staging (16.1 MB) aliases bufB (25.6 MB): staging dead before layer 2 writes bufB
  int* staging = (int*)bufB;

  // CSR build via 2-level counting sort
  hipMemsetAsync(gcursor, 0, NBUCK * sizeof(int), stream);
  bin_kernel<<<(NE + 256 * EPB - 1) / (256 * EPB), 256, 0, stream>>>(src, dst, gcursor, staging);
  build_kernel<<<NBUCK, 256, 0, stream>>>(staging, gcursor, row_off, esrc);

  // cast node_attr to fp16
  cast_f16<<<(NN * FDIM / 4 + 255) / 256, 256, 0, stream>>>((const float4*)node_attr,
                                                            (ushort4*)xh, NN * FDIM / 4);

  // fused conv layers: fp16 gather -> fp32 LDS/GEMM -> fp16 store
  conv_fused<<<(NN + 63) / 64, 512, 0, stream>>>((const ushort4*)xh, row_off, esrc,
                                                 Wc, bc, bufA);
  conv_fused<<<(NN + 63) / 64, 512, 0, stream>>>((const ushort4*)bufA, row_off, esrc,
                                                 Wc + 16384, bc + 128, bufB);
  conv_fused<<<(NN + 63) / 64, 512, 0, stream>>>((const ushort4*)bufB, row_off, esrc,
                                                 Wc + 32768, bc + 256, bufA);

  // fused pool + head
  pool_head<<<NG, 128, 0, stream>>>(bufA, batching, Wf1, bf1, Wf2, bf2, out);
}